// Round 1
// baseline (360.133 us; speedup 1.0000x reference)
//
#include <hip/hip_runtime.h>
#include <hip/hip_bf16.h>

// Conv2d: in (32,128,56,56) f32, w (256,256?,3,3)->(256,128,3,3) f32, bias(256) f32
// out (32,256,56,56) f32.  Implicit-GEMM with bf16 MFMA 16x16x32.
//
// ws layout:  [0, 1MB)            : w2  bf16 [9][256][128]   (589,824 B)
//             [1MB, 1MB+30.4MB)   : in_pad bf16 [32][58][64][128] (zero-padded NHWC)

typedef __bf16 bf16x8 __attribute__((ext_vector_type(8)));
typedef float f32x4 __attribute__((ext_vector_type(4)));

#define N_IMG 32
#define C_IN 128
#define HW 56
#define K_OUT 256
#define YPAD 58
#define XPAD 64
#define IN_PAD_OFF 1048576ul

// ---------------- pre-pass: weight OIHW f32 -> [rs][ko][c] bf16 ----------------
__global__ void prep_weight(const float* __restrict__ wt, __bf16* __restrict__ w2) {
    int o = blockIdx.x * 256 + threadIdx.x;          // 9*256*128 = 294912
    if (o >= 9 * K_OUT * C_IN) return;
    int c  = o % C_IN;
    int ko = (o / C_IN) % K_OUT;
    int rs = o / (C_IN * K_OUT);
    w2[o] = (__bf16)wt[((size_t)ko * C_IN + c) * 9 + rs];
}

// ------------- pre-pass: input NCHW f32 -> padded NHWC bf16 (zero border) -------
// one block per (n, y); LDS transpose for coalesced read AND write
__global__ void prep_input(const float* __restrict__ in, __bf16* __restrict__ in_pad) {
    int bid = blockIdx.x;                 // 32*58 = 1856
    int y = bid % YPAD;
    int n = bid / YPAD;
    int h = y - 1;
    bool interior = (h >= 0 && h < HW);
    __shared__ float tile[HW * 129];      // [w][c], pitch 129 (bank-conflict-free)
    int t = threadIdx.x;
    if (interior) {
        for (int idx = t; idx < C_IN * HW; idx += 256) {
            int c = idx / HW, w = idx % HW;
            tile[w * 129 + c] = in[((size_t)(n * C_IN + c) * HW + h) * HW + w];
        }
    }
    __syncthreads();
    __bf16* dst = in_pad + (size_t)(n * YPAD + y) * XPAD * C_IN;
    for (int idx = t; idx < XPAD * C_IN; idx += 256) {
        int x = idx / C_IN, c = idx % C_IN;
        float v = 0.f;
        if (interior && x >= 1 && x <= HW) v = tile[(x - 1) * 129 + c];
        dst[idx] = (__bf16)v;
    }
}

// ---------------- main kernel: implicit-GEMM conv, register-only MFMA ----------
// block: 256 thr = 4 waves (2 mw x 2 nw). Tile: 128 M (8h x 16w) x 128 N (ko).
// grid: 32 n * 7 ht * 4 wt * 2 kot = 1792.  Last w-tile overlaps (w0=40) -> no masks.
__global__ __launch_bounds__(256, 3) void conv_mfma(
        const __bf16* __restrict__ in_pad,   // [32][58][64][128]
        const __bf16* __restrict__ w2,       // [9][256][128]
        const float* __restrict__ bias,
        float* __restrict__ out)             // [32][256][56][56]
{
    int bid  = blockIdx.x;
    int kot  = bid & 1;
    int wt_  = (bid >> 1) & 3;
    int rest = bid >> 3;
    int ht   = rest % 7;
    int n    = rest / 7;

    int h0  = ht * 8;
    int w0  = (wt_ == 3) ? 40 : wt_ * 16;
    int ko0 = kot * 128;

    int tid  = threadIdx.x;
    int lane = tid & 63;
    int wave = tid >> 6;
    int mw   = wave & 1;        // M half (64 rows = 4 h)
    int nw   = wave >> 1;       // N half (64 ko)
    int l15  = lane & 15;
    int quad = lane >> 4;

    f32x4 acc[4][4] = {};

    // A: in_pad[n][y = h0+mw*4 + (i+r)][x = w0 + l15 + s][c = c0 + quad*8]
    const __bf16* a_base = in_pad
        + ((size_t)((n * YPAD + h0 + mw * 4)) * XPAD + w0 + l15) * C_IN + quad * 8;
    // B: w2[rs][ko = ko0 + nw*64 + j*16 + l15][c = c0 + quad*8]
    const __bf16* b_base = w2 + (size_t)(ko0 + nw * 64 + l15) * C_IN + quad * 8;

#pragma unroll 1
    for (int c0 = 0; c0 < C_IN; c0 += 32) {
#pragma unroll
        for (int s = 0; s < 3; ++s) {
            bf16x8 a6[6];
#pragma unroll
            for (int t6 = 0; t6 < 6; ++t6)
                a6[t6] = *(const bf16x8*)(a_base + (t6 * XPAD + s) * C_IN + c0);
#pragma unroll
            for (int r = 0; r < 3; ++r) {
                int rs = r * 3 + s;
                bf16x8 b[4];
#pragma unroll
                for (int j = 0; j < 4; ++j)
                    b[j] = *(const bf16x8*)(b_base + rs * (K_OUT * C_IN) + j * 16 * C_IN + c0);
#pragma unroll
                for (int i = 0; i < 4; ++i)
#pragma unroll
                    for (int j = 0; j < 4; ++j)
                        acc[i][j] = __builtin_amdgcn_mfma_f32_16x16x32_bf16(
                            a6[i + r], b[j], acc[i][j], 0, 0, 0);
            }
        }
    }

    // epilogue: D[row=quad*4+reg][col=l15] ; row -> dw, col -> ko-within-16
#pragma unroll
    for (int j = 0; j < 4; ++j) {
        int ko = ko0 + nw * 64 + j * 16 + l15;
        float bs = bias[ko];
        float* outb = out + (size_t)(n * K_OUT + ko) * (HW * HW)
                          + (size_t)(h0 + mw * 4) * HW + w0 + quad * 4;
#pragma unroll
        for (int i = 0; i < 4; ++i) {
            f32x4 v = acc[i][j];
            v = v + bs;
            *(f32x4*)(outb + i * HW) = v;
        }
    }
}

// ---------------- fallback: naive direct conv (only if ws too small) -----------
__global__ void conv_naive(const float* __restrict__ in, const float* __restrict__ wt,
                           const float* __restrict__ bias, float* __restrict__ out) {
    size_t idx = (size_t)blockIdx.x * 256 + threadIdx.x;
    size_t total = (size_t)N_IMG * K_OUT * HW * HW;
    if (idx >= total) return;
    int w  = idx % HW;
    int h  = (idx / HW) % HW;
    int ko = (idx / (HW * HW)) % K_OUT;
    int n  = idx / ((size_t)HW * HW * K_OUT);
    float acc = bias[ko];
    for (int c = 0; c < C_IN; ++c)
        for (int r = 0; r < 3; ++r) {
            int y = h + r - 1;
            if (y < 0 || y >= HW) continue;
            for (int s = 0; s < 3; ++s) {
                int x = w + s - 1;
                if (x < 0 || x >= HW) continue;
                acc += in[((size_t)(n * C_IN + c) * HW + y) * HW + x]
                     * wt[((size_t)ko * C_IN + c) * 9 + r * 3 + s];
            }
        }
    out[idx] = acc;
}

extern "C" void kernel_launch(void* const* d_in, const int* in_sizes, int n_in,
                              void* d_out, int out_size, void* d_ws, size_t ws_size,
                              hipStream_t stream) {
    const float* in   = (const float*)d_in[0];
    const float* wt   = (const float*)d_in[1];
    const float* bias = (const float*)d_in[2];
    float* out = (float*)d_out;

    size_t need = IN_PAD_OFF + (size_t)N_IMG * YPAD * XPAD * C_IN * 2;
    if (ws_size >= need) {
        __bf16* w2     = (__bf16*)d_ws;
        __bf16* in_pad = (__bf16*)((char*)d_ws + IN_PAD_OFF);
        prep_weight<<<(9 * K_OUT * C_IN + 255) / 256, 256, 0, stream>>>(wt, w2);
        prep_input<<<N_IMG * YPAD, 256, 0, stream>>>(in, in_pad);
        conv_mfma<<<N_IMG * 7 * 4 * 2, 256, 0, stream>>>(in_pad, w2, bias, out);
    } else {
        size_t total = (size_t)N_IMG * K_OUT * HW * HW;
        conv_naive<<<(unsigned)((total + 255) / 256), 256, 0, stream>>>(in, wt, bias, out);
    }
}

// Round 2
// 228.414 us; speedup vs baseline: 1.5767x; 1.5767x over previous
//
#include <hip/hip_runtime.h>
#include <hip/hip_bf16.h>

// Conv2d: in (32,128,56,56) f32, w (256,128,3,3) f32, bias(256) f32
// out (32,256,56,56) f32.  Implicit-GEMM, bf16 MFMA 16x16x32, m97-style
// LDS staging via global_load_lds width=16.
//
// ws:  [0, 1MB)           : w2  bf16 [9][256][128]
//      [1MB, 1MB+30.4MB)  : in_pad bf16 [32][58][64][128] (zero-padded NHWC)

typedef __bf16 bf16x8 __attribute__((ext_vector_type(8)));
typedef float f32x4 __attribute__((ext_vector_type(4)));

#define N_IMG 32
#define C_IN 128
#define HW 56
#define K_OUT 256
#define YPAD 58
#define XPAD 64
#define IN_PAD_OFF 1048576ul

__device__ __forceinline__ void gl_lds16(const __bf16* g, __bf16* l) {
    __builtin_amdgcn_global_load_lds(
        (const __attribute__((address_space(1))) unsigned int*)(const void*)g,
        (__attribute__((address_space(3))) unsigned int*)(void*)l,
        16, 0, 0);
}

// ---------------- pre-pass: weight OIHW f32 -> [rs][ko][c] bf16 (16B stores) ---
__global__ void prep_weight(const float* __restrict__ wt, __bf16* __restrict__ w2) {
    int idx = blockIdx.x * 256 + threadIdx.x;   // 9*256*16 = 36864 items
    if (idx >= 9 * K_OUT * 16) return;
    int c8 = idx & 15;
    int ko = (idx >> 4) & 255;
    int rs = idx >> 12;
    const float* src = wt + ((size_t)ko * C_IN + c8 * 8) * 9 + rs;
    bf16x8 v8;
#pragma unroll
    for (int k = 0; k < 8; ++k) v8[k] = (__bf16)src[k * 9];
    *(bf16x8*)(w2 + (size_t)idx * 8) = v8;      // = [rs][ko][c8*8..+8]
}

// ------------- pre-pass: input NCHW f32 -> padded NHWC bf16 (vectorized) -------
__global__ void prep_input(const float* __restrict__ in, __bf16* __restrict__ in_pad) {
    int bid = blockIdx.x;                 // 32*58 = 1856
    int y = bid % YPAD;
    int n = bid / YPAD;
    int h = y - 1;
    bool interior = (h >= 0 && h < HW);
    __shared__ float tile[HW * 130];      // [w][c], pitch 130
    int t = threadIdx.x;
    if (interior) {
        const float* src = in + (size_t)n * C_IN * (HW * HW) + (size_t)h * HW;
#pragma unroll 1
        for (int idx = t; idx < C_IN * 14; idx += 256) {   // float4 reads
            int c = idx / 14, g = idx % 14;
            f32x4 v = *(const f32x4*)(src + (size_t)c * (HW * HW) + g * 4);
            int w = g * 4;
            tile[(w + 0) * 130 + c] = v.x;
            tile[(w + 1) * 130 + c] = v.y;
            tile[(w + 2) * 130 + c] = v.z;
            tile[(w + 3) * 130 + c] = v.w;
        }
    }
    __syncthreads();
    __bf16* dst = in_pad + (size_t)(n * YPAD + y) * XPAD * C_IN;
#pragma unroll 1
    for (int idx = t; idx < XPAD * 16; idx += 256) {       // 16B stores
        int x = idx >> 4, cg = idx & 15;
        bf16x8 v8;
        if (interior && x >= 1 && x <= HW) {
            const float* tp = tile + (x - 1) * 130 + cg * 8;
#pragma unroll
            for (int k = 0; k < 8; ++k) v8[k] = (__bf16)tp[k];
        } else {
#pragma unroll
            for (int k = 0; k < 8; ++k) v8[k] = (__bf16)0.f;
        }
        *(bf16x8*)(dst + x * C_IN + cg * 8) = v8;
    }
}

// ---------------- main kernel: LDS-staged implicit-GEMM conv -------------------
// block 256 thr = 4 waves (2 mw x 2 nw), tile 128M (8h x 16w) x 128N (ko).
// K-loop: 9 rs x 2 c64 = 18 stages; per stage: stage A(16KB)+B(16KB) via
// global_load_lds, then per wave 16 ds_read_b128 + 32 MFMA.
// LDS chunk swizzle: 16B chunk cc stored at cc ^ (x&7) (A) / cc ^ (ko&7) (B).
__global__ __launch_bounds__(256, 4) void conv_mfma(
        const __bf16* __restrict__ in_pad,   // [32][58][64][128]
        const __bf16* __restrict__ w2,       // [9][256][128]
        const float* __restrict__ bias,
        float* __restrict__ out)             // [32][256][56][56]
{
    __shared__ __bf16 sA[8 * 16 * 64];       // 16 KB  [i][x][c64 chunks, swizzled]
    __shared__ __bf16 sB[128 * 64];          // 16 KB  [ko][c64 chunks, swizzled]

    int bid  = blockIdx.x;
    int kot  = bid & 1;
    int wt_  = (bid >> 1) & 3;
    int rest = bid >> 3;
    int ht   = rest % 7;
    int n    = rest / 7;

    int h0  = ht * 8;
    int w0  = (wt_ == 3) ? 40 : wt_ * 16;    // last w-tile overlaps: no masks
    int ko0 = kot * 128;

    int tid  = threadIdx.x;
    int lane = tid & 63;
    int wave = tid >> 6;
    int mw   = wave & 1;
    int nw   = wave >> 1;
    int l15  = lane & 15;
    int quad = lane >> 4;

    // per-thread staging source offsets (element units), swizzle baked in
    int aoff[4], boff[4];
#pragma unroll
    for (int q = 0; q < 4; ++q) {
        int chunk = q * 256 + tid;           // 0..1023 (16B chunks)
        int i  = chunk >> 7;                 // A: [i(8)][x(16)][cc(8)]
        int x  = (chunk >> 3) & 15;
        int cs = chunk & 7;
        aoff[q] = (i * XPAD + x) * C_IN + (cs ^ (x & 7)) * 8;
        int ko = chunk >> 3;                 // B: [ko(128)][cc(8)]
        boff[q] = ko * C_IN + (cs ^ (ko & 7)) * 8;
    }

    // fragment ds_read element offsets
    int ac0   = quad ^ (l15 & 7);            // swizzled chunk idx, ks toggles bit2
    int aBase = (mw * 64 + l15) * 64;        // elem = i*1024 + x*64 + cc*8
    int bBase = (nw * 64 + l15) * 64;        // elem = ko*64 + cc*8

    const __bf16* aG = in_pad + (((size_t)n * YPAD + h0) * XPAD + w0) * C_IN;
    const __bf16* bG = w2 + (size_t)ko0 * C_IN;

    f32x4 acc[4][4] = {};

#pragma unroll 1
    for (int r = 0; r < 3; ++r) {
#pragma unroll 1
        for (int s = 0; s < 3; ++s) {
            const __bf16* aStage = aG + (r * XPAD + s) * C_IN;
            const __bf16* bStage = bG + (size_t)(r * 3 + s) * (K_OUT * C_IN);
#pragma unroll 1
            for (int c0 = 0; c0 < C_IN; c0 += 64) {
                __syncthreads();
#pragma unroll
                for (int q = 0; q < 4; ++q)
                    gl_lds16(aStage + c0 + aoff[q], sA + q * 2048 + wave * 512);
#pragma unroll
                for (int q = 0; q < 4; ++q)
                    gl_lds16(bStage + c0 + boff[q], sB + q * 2048 + wave * 512);
                __syncthreads();
#pragma unroll
                for (int ks = 0; ks < 2; ++ks) {
                    int coff = (ac0 ^ (ks << 2)) * 8;
                    bf16x8 a[4], b[4];
#pragma unroll
                    for (int mf = 0; mf < 4; ++mf)
                        a[mf] = *(const bf16x8*)(sA + aBase + mf * 1024 + coff);
#pragma unroll
                    for (int nf = 0; nf < 4; ++nf)
                        b[nf] = *(const bf16x8*)(sB + bBase + nf * 1024 + coff);
#pragma unroll
                    for (int mf = 0; mf < 4; ++mf)
#pragma unroll
                        for (int nf = 0; nf < 4; ++nf)
                            acc[mf][nf] = __builtin_amdgcn_mfma_f32_16x16x32_bf16(
                                a[mf], b[nf], acc[mf][nf], 0, 0, 0);
                }
            }
        }
    }

    // epilogue: D[row=quad*4+reg][col=l15]; row -> w, col -> ko-within-16
#pragma unroll
    for (int nf = 0; nf < 4; ++nf) {
        int ko = ko0 + nw * 64 + nf * 16 + l15;
        float bs = bias[ko];
        float* outb = out + (size_t)(n * K_OUT + ko) * (HW * HW)
                          + (size_t)(h0 + mw * 4) * HW + w0 + quad * 4;
#pragma unroll
        for (int mf = 0; mf < 4; ++mf) {
            f32x4 v = acc[mf][nf];
            v = v + bs;
            *(f32x4*)(outb + mf * HW) = v;
        }
    }
}

// ---------------- fallback: naive direct conv (only if ws too small) -----------
__global__ void conv_naive(const float* __restrict__ in, const float* __restrict__ wt,
                           const float* __restrict__ bias, float* __restrict__ out) {
    size_t idx = (size_t)blockIdx.x * 256 + threadIdx.x;
    size_t total = (size_t)N_IMG * K_OUT * HW * HW;
    if (idx >= total) return;
    int w  = idx % HW;
    int h  = (idx / HW) % HW;
    int ko = (idx / (HW * HW)) % K_OUT;
    int n  = idx / ((size_t)HW * HW * K_OUT);
    float acc = bias[ko];
    for (int c = 0; c < C_IN; ++c)
        for (int r = 0; r < 3; ++r) {
            int y = h + r - 1;
            if (y < 0 || y >= HW) continue;
            for (int s = 0; s < 3; ++s) {
                int x = w + s - 1;
                if (x < 0 || x >= HW) continue;
                acc += in[((size_t)(n * C_IN + c) * HW + y) * HW + x]
                     * wt[((size_t)ko * C_IN + c) * 9 + r * 3 + s];
            }
        }
    out[idx] = acc;
}

extern "C" void kernel_launch(void* const* d_in, const int* in_sizes, int n_in,
                              void* d_out, int out_size, void* d_ws, size_t ws_size,
                              hipStream_t stream) {
    const float* in   = (const float*)d_in[0];
    const float* wt   = (const float*)d_in[1];
    const float* bias = (const float*)d_in[2];
    float* out = (float*)d_out;

    size_t need = IN_PAD_OFF + (size_t)N_IMG * YPAD * XPAD * C_IN * 2;
    if (ws_size >= need) {
        __bf16* w2     = (__bf16*)d_ws;
        __bf16* in_pad = (__bf16*)((char*)d_ws + IN_PAD_OFF);
        prep_weight<<<(9 * K_OUT * 16 + 255) / 256, 256, 0, stream>>>(wt, w2);
        prep_input<<<N_IMG * YPAD, 256, 0, stream>>>(in, in_pad);
        conv_mfma<<<N_IMG * 7 * 4 * 2, 256, 0, stream>>>(in_pad, w2, bias, out);
    } else {
        size_t total = (size_t)N_IMG * K_OUT * HW * HW;
        conv_naive<<<(unsigned)((total + 255) / 256), 256, 0, stream>>>(in, wt, bias, out);
    }
}